// Round 5
// baseline (256.223 us; speedup 1.0000x reference)
//
#include <hip/hip_runtime.h>
#include <stdint.h>

#define S_LEN 4096
#define HDIM  768
#define NHEAD 12
#define DHEAD 64

typedef _Float16 f16;
typedef __attribute__((ext_vector_type(8)))  _Float16 f16x8;
typedef __attribute__((ext_vector_type(4)))  _Float16 f16x4;
typedef __attribute__((ext_vector_type(4)))  float    f32x4;
typedef __attribute__((ext_vector_type(16))) float    f32x16;

typedef __attribute__((address_space(1))) void gv_t;
typedef __attribute__((address_space(3))) void lv_t;

__device__ __forceinline__ void async_copy16(const void* g, void* l) {
  __builtin_amdgcn_global_load_lds((gv_t*)g, (lv_t*)l, 16, 0, 0);
}

__device__ __forceinline__ float fast_exp2(float x) {
#if __has_builtin(__builtin_amdgcn_exp2f)
  return __builtin_amdgcn_exp2f(x);
#else
  return exp2f(x);
#endif
}

__device__ __forceinline__ int swz4(int row) { return (row ^ (row >> 2)) & 3; }

// ---------------- workspace layout (42.5 MB, heavy reuse) ----------------
constexpr size_t OFF_META = 0;                          // int kcount
constexpr size_t OFF_POS  = 256;                        // int[4096]
constexpr size_t OFF_XB   = 65536;                      // f16 x[4096*768]; later ctx
constexpr size_t SZ_XB    = (size_t)S_LEN * HDIM * 2;
constexpr size_t OFF_WQKV = OFF_XB + SZ_XB;             // f16[3*768*768]; later PL
constexpr size_t SZ_WQKV  = (size_t)3 * HDIM * HDIM * 2;
constexpr size_t OFF_WO   = OFF_WQKV + SZ_WQKV;         // f16[768*768]
constexpr size_t SZ_WO    = (size_t)HDIM * HDIM * 2;
constexpr size_t OFF_Q    = OFF_WO + SZ_WO;             // f16[12][4096][64]
constexpr size_t SZ_HD    = (size_t)NHEAD * S_LEN * DHEAD * 2;
constexpr size_t OFF_K    = OFF_Q + SZ_HD;              // f16[12][4096][64] compacted (pre-zeroed)
constexpr size_t OFF_VT   = OFF_K + SZ_HD;              // f16[12][64][4096] transposed+permuted V
constexpr size_t OFF_VR   = OFF_VT + SZ_HD;             // f16[12][4096][64] V rows; later PO split0
constexpr size_t OFF_PO1  = OFF_VR + SZ_HD;             // f16[12][4096][64] PO split1

// ---------------- prep: fp32->fp16 convert + zero Kc + mask compaction ----------------
__global__ __launch_bounds__(256) void k_prep(const float* __restrict__ x,
                                              const float* __restrict__ wq,
                                              const float* __restrict__ wk,
                                              const float* __restrict__ wv,
                                              const float* __restrict__ wo,
                                              const int* __restrict__ mi,
                                              f16* __restrict__ dst,
                                              f16* __restrict__ Kc,
                                              int* __restrict__ pos,
                                              int* __restrict__ meta) {
  __shared__ int s_flag;
  __shared__ int s_cnt[256];
  const int b = blockIdx.x, tid = threadIdx.x;
  if (b < 5376) {
    int i = b * 256 + tid;                   // 1376256 float4 units
    const float* src; int off;
    if (i < 786432) { src = x; off = i; }
    else {
      int j = i - 786432;
      int w = j / 147456;
      off = j - w * 147456;
      src = (w == 0) ? wq : (w == 1) ? wk : (w == 2) ? wv : wo;
    }
    float4 v = ((const float4*)src)[off];
    f16x4 h;
    h[0] = (f16)v.x; h[1] = (f16)v.y; h[2] = (f16)v.z; h[3] = (f16)v.w;
    ((f16x4*)dst)[i] = h;
    return;
  }
  if (b < 6144) {
    int u = (b - 5376) * 512 + tid;
    f16x8 z = {};
    ((f16x8*)Kc)[u] = z;
    ((f16x8*)Kc)[u + 256] = z;
    return;
  }
  // ---- mask block ----
  if (tid == 0) s_flag = 1;
  __syncthreads();
  int bad = 0;
  #pragma unroll
  for (int k = 0; k < 4; ++k) {
    int v = mi[k * 256 + tid];
    if (v != 0 && v != 1) bad = 1;
  }
  if (bad) atomicAnd(&s_flag, 0);
  __syncthreads();
  const int isInt = s_flag;
  const unsigned char* mu8 = (const unsigned char*)mi;
  int keep[16]; int cnt = 0;
  const int s0 = tid * 16;
  #pragma unroll
  for (int k = 0; k < 16; ++k) {
    int mval = isInt ? mi[s0 + k] : (int)mu8[s0 + k];
    keep[k] = (mval == 0) ? 1 : 0;           // True => masked out (excluded)
    cnt += keep[k];
  }
  s_cnt[tid] = cnt;
  __syncthreads();
  for (int off = 1; off < 256; off <<= 1) {
    int t = (tid >= off) ? s_cnt[tid - off] : 0;
    __syncthreads();
    s_cnt[tid] += t;
    __syncthreads();
  }
  int base = s_cnt[tid] - cnt;
  #pragma unroll
  for (int k = 0; k < 16; ++k) {
    pos[s0 + k] = keep[k] ? base : -1;
    base += keep[k];
  }
  if (tid == 255) meta[0] = s_cnt[255];
}

// ---------------- fused QKV projection GEMM ----------------
__global__ __launch_bounds__(256) void k_qkv(
    const f16* __restrict__ xb, const f16* __restrict__ wqkv,
    const float* __restrict__ bq, const float* __restrict__ bk, const float* __restrict__ bv,
    const int* __restrict__ pos,
    f16* __restrict__ Qh, f16* __restrict__ Kc, f16* __restrict__ Vrow) {
  __shared__ __attribute__((aligned(16))) f16 lA[128 * 32];
  __shared__ __attribute__((aligned(16))) f16 lB[128 * 32];
  const int tid = threadIdx.x;
  const int wid = tid >> 6, lane = tid & 63;
  const int quad = lane >> 4, l16 = lane & 15;
  const int wm = wid >> 1, wn = wid & 1;
  const int tn = blockIdx.x;
  const int m0 = blockIdx.y * 128;
  const int mat = tn / 6;
  const int nb = (tn % 6) * 128;
  const f16* wbase = wqkv + (size_t)mat * HDIM * HDIM;

  f32x4 acc[4][4] = {};

  for (int k0 = 0; k0 < HDIM; k0 += 32) {
    #pragma unroll
    for (int iss = 0; iss < 2; ++iss) {
      int c = iss * 256 + tid;
      int row = c >> 2, slot = c & 3;
      int gs = slot ^ swz4(row);
      async_copy16((const char*)(xb + (size_t)(m0 + row) * HDIM + k0) + gs * 16,
                   (char*)lA + (iss * 256 + wid * 64) * 16);
      async_copy16((const char*)(wbase + (size_t)(nb + row) * HDIM + k0) + gs * 16,
                   (char*)lB + (iss * 256 + wid * 64) * 16);
    }
    __syncthreads();
    f16x8 af[4], bf[4];
    #pragma unroll
    for (int mi = 0; mi < 4; ++mi) {
      int row = wm * 64 + mi * 16 + l16;
      af[mi] = *(const f16x8*)&lA[row * 32 + (quad ^ swz4(row)) * 8];
    }
    #pragma unroll
    for (int ni = 0; ni < 4; ++ni) {
      int row = wn * 64 + ni * 16 + l16;
      bf[ni] = *(const f16x8*)&lB[row * 32 + (quad ^ swz4(row)) * 8];
    }
    #pragma unroll
    for (int mi = 0; mi < 4; ++mi)
      #pragma unroll
      for (int ni = 0; ni < 4; ++ni)
        acc[mi][ni] = __builtin_amdgcn_mfma_f32_16x16x32_f16(af[mi], bf[ni], acc[mi][ni], 0, 0, 0);
    __syncthreads();
  }

  const float* bias = (mat == 0) ? bq : (mat == 1) ? bk : bv;
  const float qscale = 0.125f * 1.44269504088896341f;  // 1/sqrt(64) * log2(e)
  f16* kvdst = (mat == 1) ? Kc : Vrow;
  #pragma unroll
  for (int mi = 0; mi < 4; ++mi) {
    int srow = m0 + wm * 64 + mi * 16 + quad * 4;
    #pragma unroll
    for (int ni = 0; ni < 4; ++ni) {
      int n = nb + wn * 64 + ni * 16 + l16;
      int head = n >> 6, d = n & 63;
      float b = bias[n];
      #pragma unroll
      for (int r = 0; r < 4; ++r) {
        int s = srow + r;
        float val = acc[mi][ni][r] + b;
        if (mat == 0) {
          Qh[((size_t)head * S_LEN + s) * DHEAD + d] = (f16)(val * qscale);
        } else {
          int p = pos[s];
          if (p >= 0)
            kvdst[((size_t)head * S_LEN + p) * DHEAD + d] = (f16)val;
        }
      }
    }
  }
}

// ---------------- V transpose [h][p][d] -> [h][d][rho], key order bit-swapped ----------------
// rho-position holds key with bits 2<->3 swapped (within each 16-group), so that the PV
// A-fragment in k_attn is the lane's own contiguous C-regs (no cross-lane exchange).
__global__ __launch_bounds__(256) void k_vt(const int* __restrict__ meta,
                                            const f16* __restrict__ Vrow,
                                            f16* __restrict__ Vtc) {
  const int kc = meta[0];
  const int kcp = (kc + 63) & ~63;
  const int p0 = blockIdx.x * 64;
  const int h = blockIdx.y;
  if (p0 >= kcp) return;
  __shared__ __attribute__((aligned(16))) f16 lT[64 * 80];   // [d][p], stride 80
  const int tid = threadIdx.x;
  for (int u = tid; u < 512; u += 256) {
    int d8 = u >> 6, p = u & 63;
    f16x8 v = {};
    if (p0 + p < kc) v = *(const f16x8*)&Vrow[((size_t)h * S_LEN + p0 + p) * DHEAD + d8 * 8];
    #pragma unroll
    for (int j = 0; j < 8; ++j) lT[(d8 * 8 + j) * 80 + p] = v[j];
  }
  __syncthreads();
  for (int w = tid; w < 512; w += 256) {
    int d = w >> 3, p8 = w & 7;
    int base16 = (p8 >> 1) * 16, half = p8 & 1;
    f16x4 lo = *(const f16x4*)&lT[d * 80 + base16 + half * 4];
    f16x4 hi = *(const f16x4*)&lT[d * 80 + base16 + 8 + half * 4];
    f16x8 o;
    o[0] = lo[0]; o[1] = lo[1]; o[2] = lo[2]; o[3] = lo[3];
    o[4] = hi[0]; o[5] = hi[1]; o[6] = hi[2]; o[7] = hi[3];
    *(f16x8*)&Vtc[((size_t)h * DHEAD + d) * S_LEN + p0 + p8 * 8] = o;
  }
}

// ---------------- flash attention: 64q/wave, register-P, in-block key-stream split ----------
// grid (32 q-tiles of 128, 12 heads, 2 global key-splits).
// 4 waves = 2 q-groups x 2 key-streams; each stream stages its own 16KB K/V tile.
// S^T = K.Q^T; P = exp2(S^T) stays in C-regs; PV A-frag = own regs (V key-permuted).
__global__ __launch_bounds__(256, 3) void k_attn(
    const f16* __restrict__ Qh, const f16* __restrict__ Kc, const f16* __restrict__ Vtc,
    const int* __restrict__ meta, f16* __restrict__ PO0, f16* __restrict__ PO1,
    float* __restrict__ PL) {
  __shared__ __attribute__((aligned(16))) f16 lbuf[2][2][64 * 64];  // [ks][K|V][row][64]
  __shared__ float lcomb[2][64];                                    // l partials from ks=1
  const int tid = threadIdx.x;
  const int wid = tid >> 6, lane = tid & 63;
  const int hf = lane >> 5, l31 = lane & 31;
  const int qg = wid & 1, ks = wid >> 1;
  const int head = blockIdx.y;
  const int split = blockIdx.z;
  const int qbase = blockIdx.x * 128 + qg * 64;
  const int kc = meta[0];
  const int nkt = (kc + 63) >> 6;
  const int th = nkt >> 1;
  const int t0 = split ? th : 0;
  const int t1 = split ? nkt : th;
  const int nloop = (t1 - t0 + 1) >> 1;

  // Q B-frags: lane n = q' = l31, k = dc*16 + hf*8 + j
  f16x8 qf[2][4];
  #pragma unroll
  for (int qh = 0; qh < 2; ++qh) {
    const f16* Qp = Qh + ((size_t)head * S_LEN + qbase + qh * 32 + l31) * DHEAD;
    #pragma unroll
    for (int dc = 0; dc < 4; ++dc)
      qf[qh][dc] = *(const f16x8*)(Qp + dc * 16 + hf * 8);
  }

  f32x16 accO[2][2] = {};      // [qh][dh]
  float lsum[2] = {0.f, 0.f};

  const char* kbase = (const char*)(Kc + (size_t)head * S_LEN * DHEAD);
  const char* vbase = (const char*)(Vtc + (size_t)head * DHEAD * S_LEN);
  f16* myK = &lbuf[ks][0][0];
  f16* myV = &lbuf[ks][1][0];
  const int srow = lane >> 3, sslot = lane & 7;

  for (int i = 0; i < nloop; ++i) {
    const int t = t0 + 2 * i + ks;
    const bool active = t < t1;
    if (active) {
      const int j0 = t * 64;
      if (qg == 0) {
        #pragma unroll
        for (int r = 0; r < 8; ++r) {
          int row = r * 8 + srow;
          int gs = sslot ^ (row & 7);
          async_copy16(kbase + (size_t)(j0 + row) * 128 + gs * 16, (char*)myK + r * 1024);
        }
      } else {
        #pragma unroll
        for (int r = 0; r < 8; ++r) {
          int d = r * 8 + srow;
          int gs = sslot ^ (d & 7);
          async_copy16(vbase + (size_t)d * (S_LEN * 2) + (size_t)j0 * 2 + gs * 16,
                       (char*)myV + r * 1024);
        }
      }
    }
    __syncthreads();
    if (active) {
      #pragma unroll
      for (int mh = 0; mh < 2; ++mh) {
        // K A-frags: lane m = key = mh*32 + l31, k = dc*16 + hf*8 + j
        f16x8 af[4];
        const int arow = mh * 32 + l31;
        #pragma unroll
        for (int dc = 0; dc < 4; ++dc) {
          int c = dc * 2 + hf;
          af[dc] = *(const f16x8*)&myK[arow * 64 + ((c ^ (arow & 7)) * 8)];
        }
        #pragma unroll
        for (int qh = 0; qh < 2; ++qh) {
          f32x16 s = {};
          #pragma unroll
          for (int dc = 0; dc < 4; ++dc)
            s = __builtin_amdgcn_mfma_f32_32x32x16_f16(af[dc], qf[qh][dc], s, 0, 0, 0);
          float ls = 0.f;
          #pragma unroll
          for (int u = 0; u < 16; ++u) { s[u] = fast_exp2(s[u]); ls += s[u]; }
          lsum[qh] += ls;
          // PV: A-frag(chunk) = own C-regs [8cc..8cc+7] (V is key-permuted to match)
          #pragma unroll
          for (int cc = 0; cc < 2; ++cc) {
            f16x8 pf;
            #pragma unroll
            for (int u = 0; u < 8; ++u) pf[u] = (f16)s[8 * cc + u];
            const int kt = mh * 2 + cc;
            #pragma unroll
            for (int dh = 0; dh < 2; ++dh) {
              int vrow = dh * 32 + l31;
              int c = kt * 2 + hf;
              f16x8 vf = *(const f16x8*)&myV[vrow * 64 + ((c ^ (vrow & 7)) * 8)];
              accO[qh][dh] = __builtin_amdgcn_mfma_f32_32x32x16_f16(pf, vf, accO[qh][dh], 0, 0, 0);
            }
          }
        }
      }
    }
    __syncthreads();
  }

  // fold hf halves of l (each lane summed only its 16 of 32 key-rows)
  lsum[0] += __shfl_xor(lsum[0], 32);
  lsum[1] += __shfl_xor(lsum[1], 32);
  // pad keys (zero K rows -> P=1 exactly): subtract from the stream that ran the last tile
  const float npadf = (float)(nkt * 64 - kc);
  if (split == 1 && (((nkt - 1 - t0) & 1) == ks)) { lsum[0] -= npadf; lsum[1] -= npadf; }

  // in-block combine of the 2 key-streams (fp32 through LDS)
  // per qg: 64 q-rows x 64 d = 4096 floats; both qg = 8192 floats = 32KB = lbuf exactly
  float* ocomb = (float*)&lbuf[0][0][0];
  if (ks == 1) {
    #pragma unroll
    for (int qh = 0; qh < 2; ++qh) {
      #pragma unroll
      for (int dh = 0; dh < 2; ++dh)
        #pragma unroll
        for (int reg = 0; reg < 16; ++reg) {
          int row = qh * 32 + (reg & 3) + 8 * (reg >> 2) + 4 * hf;
          ocomb[qg * 4096 + row * 64 + dh * 32 + l31] = accO[qh][dh][reg];
        }
      if (hf == 0) lcomb[qg][qh * 32 + l31] = lsum[qh];
    }
  }
  __syncthreads();
  if (ks == 0) {
    f16* PO = split ? PO1 : PO0;
    #pragma unroll
    for (int qh = 0; qh < 2; ++qh) {
      #pragma unroll
      for (int dh = 0; dh < 2; ++dh)
        #pragma unroll
        for (int reg = 0; reg < 16; ++reg) {
          int row = qh * 32 + (reg & 3) + 8 * (reg >> 2) + 4 * hf;
          float v = accO[qh][dh][reg] + ocomb[qg * 4096 + row * 64 + dh * 32 + l31];
          int sidx = qbase + row;
          PO[((size_t)head * S_LEN + sidx) * DHEAD + dh * 32 + l31] = (f16)v;
        }
      if (hf == 0)
        PL[((size_t)split * NHEAD + head) * S_LEN + qbase + qh * 32 + l31] =
            lsum[qh] + lcomb[qg][qh * 32 + l31];
    }
  }
}

// ---------------- combine key-split partials -> ctx ----------------
__global__ __launch_bounds__(256) void k_comb(const f16* __restrict__ PO0,
                                              const f16* __restrict__ PO1,
                                              const float* __restrict__ PL,
                                              f16* __restrict__ ctx) {
  int u = blockIdx.x * 256 + threadIdx.x;    // 4096 rows * 96 8-wide units
  int s = u / 96;
  int c = u - s * 96;
  int h = c >> 3, db = (c & 7) * 8;
  size_t i0 = ((size_t)h * S_LEN + s) * DHEAD + db;
  f16x8 o0 = *(const f16x8*)(PO0 + i0);
  f16x8 o1 = *(const f16x8*)(PO1 + i0);
  float l = PL[(size_t)h * S_LEN + s] + PL[(size_t)(NHEAD + h) * S_LEN + s];
  float inv = 1.0f / l;
  f16x8 o;
  #pragma unroll
  for (int i = 0; i < 8; ++i) o[i] = (f16)(((float)o0[i] + (float)o1[i]) * inv);
  *(f16x8*)(ctx + (size_t)s * HDIM + h * DHEAD + db) = o;
}

// ---------------- output projection GEMM (fp32 out) ----------------
__global__ __launch_bounds__(256) void k_out(
    const f16* __restrict__ ctx, const f16* __restrict__ wo,
    const float* __restrict__ bo, float* __restrict__ out) {
  __shared__ __attribute__((aligned(16))) f16 lA[128 * 32];
  __shared__ __attribute__((aligned(16))) f16 lB[128 * 32];
  const int tid = threadIdx.x;
  const int wid = tid >> 6, lane = tid & 63;
  const int quad = lane >> 4, l16 = lane & 15;
  const int wm = wid >> 1, wn = wid & 1;
  const int nb = blockIdx.x * 128;
  const int m0 = blockIdx.y * 128;

  f32x4 acc[4][4] = {};

  for (int k0 = 0; k0 < HDIM; k0 += 32) {
    #pragma unroll
    for (int iss = 0; iss < 2; ++iss) {
      int c = iss * 256 + tid;
      int row = c >> 2, slot = c & 3;
      int gs = slot ^ swz4(row);
      async_copy16((const char*)(ctx + (size_t)(m0 + row) * HDIM + k0) + gs * 16,
                   (char*)lA + (iss * 256 + wid * 64) * 16);
      async_copy16((const char*)(wo + (size_t)(nb + row) * HDIM + k0) + gs * 16,
                   (char*)lB + (iss * 256 + wid * 64) * 16);
    }
    __syncthreads();
    f16x8 af[4], bf[4];
    #pragma unroll
    for (int mi = 0; mi < 4; ++mi) {
      int row = wm * 64 + mi * 16 + l16;
      af[mi] = *(const f16x8*)&lA[row * 32 + (quad ^ swz4(row)) * 8];
    }
    #pragma unroll
    for (int ni = 0; ni < 4; ++ni) {
      int row = wn * 64 + ni * 16 + l16;
      bf[ni] = *(const f16x8*)&lB[row * 32 + (quad ^ swz4(row)) * 8];
    }
    #pragma unroll
    for (int mi = 0; mi < 4; ++mi)
      #pragma unroll
      for (int ni = 0; ni < 4; ++ni)
        acc[mi][ni] = __builtin_amdgcn_mfma_f32_16x16x32_f16(af[mi], bf[ni], acc[mi][ni], 0, 0, 0);
    __syncthreads();
  }

  #pragma unroll
  for (int mi = 0; mi < 4; ++mi) {
    int srow = m0 + wm * 64 + mi * 16 + quad * 4;
    #pragma unroll
    for (int ni = 0; ni < 4; ++ni) {
      int n = nb + wn * 64 + ni * 16 + l16;
      float b = bo[n];
      #pragma unroll
      for (int r = 0; r < 4; ++r)
        out[(size_t)(srow + r) * HDIM + n] = acc[mi][ni][r] + b;
    }
  }
}

extern "C" void kernel_launch(void* const* d_in, const int* in_sizes, int n_in,
                              void* d_out, int out_size, void* d_ws, size_t ws_size,
                              hipStream_t stream) {
  const float* x  = (const float*)d_in[0];
  const float* Wq = (const float*)d_in[1];
  const float* bq = (const float*)d_in[2];
  const float* Wk = (const float*)d_in[3];
  const float* bk = (const float*)d_in[4];
  const float* Wv = (const float*)d_in[5];
  const float* bv = (const float*)d_in[6];
  const float* Wo = (const float*)d_in[7];
  const float* bo = (const float*)d_in[8];
  const int*   mask = (const int*)d_in[9];
  float* out = (float*)d_out;

  char* ws = (char*)d_ws;
  int* meta  = (int*)(ws + OFF_META);
  int* pos   = (int*)(ws + OFF_POS);
  f16* xb    = (f16*)(ws + OFF_XB);
  f16* wqkv  = (f16*)(ws + OFF_WQKV);
  f16* wob   = (f16*)(ws + OFF_WO);
  f16* Qh    = (f16*)(ws + OFF_Q);
  f16* Kc    = (f16*)(ws + OFF_K);
  f16* Vtc   = (f16*)(ws + OFF_VT);
  f16* Vrow  = (f16*)(ws + OFF_VR);
  f16* PO0   = (f16*)(ws + OFF_VR);     // reuses Vrow after k_vt
  f16* PO1   = (f16*)(ws + OFF_PO1);
  float* PL  = (float*)(ws + OFF_WQKV); // reuses wqkv after k_qkv
  f16* ctx   = (f16*)(ws + OFF_XB);     // reuses xb after k_qkv

  k_prep<<<dim3(6145), 256, 0, stream>>>(x, Wq, Wk, Wv, Wo, mask, xb, Kc, pos, meta);
  k_qkv<<<dim3(18, 32), 256, 0, stream>>>(xb, wqkv, bq, bk, bv, pos, Qh, Kc, Vrow);
  k_vt<<<dim3(64, NHEAD), 256, 0, stream>>>(meta, Vrow, Vtc);
  k_attn<<<dim3(32, NHEAD, 2), 256, 0, stream>>>(Qh, Kc, Vtc, meta, PO0, PO1, PL);
  k_comb<<<dim3((S_LEN * 96) / 256), 256, 0, stream>>>(PO0, PO1, PL, ctx);
  k_out<<<dim3(6, 32), 256, 0, stream>>>(ctx, wob, bo, out);
}

// Round 6
// 186.694 us; speedup vs baseline: 1.3724x; 1.3724x over previous
//
#include <hip/hip_runtime.h>
#include <stdint.h>

#define S_LEN 4096
#define HDIM  768
#define NHEAD 12
#define DHEAD 64

typedef _Float16 f16;
typedef __attribute__((ext_vector_type(8)))  _Float16 f16x8;
typedef __attribute__((ext_vector_type(4)))  _Float16 f16x4;
typedef __attribute__((ext_vector_type(4)))  float    f32x4;
typedef __attribute__((ext_vector_type(16))) float    f32x16;

typedef __attribute__((address_space(1))) void gv_t;
typedef __attribute__((address_space(3))) void lv_t;

__device__ __forceinline__ void async_copy16(const void* g, void* l) {
  __builtin_amdgcn_global_load_lds((gv_t*)g, (lv_t*)l, 16, 0, 0);
}

__device__ __forceinline__ float fast_exp2(float x) {
#if __has_builtin(__builtin_amdgcn_exp2f)
  return __builtin_amdgcn_exp2f(x);
#else
  return exp2f(x);
#endif
}

__device__ __forceinline__ int swz4(int row) { return (row ^ (row >> 2)) & 3; }

// ---------------- workspace layout (42.5 MB, heavy reuse) ----------------
constexpr size_t OFF_META = 0;                          // int kcount
constexpr size_t OFF_POS  = 256;                        // int[4096]
constexpr size_t OFF_XB   = 65536;                      // f16 x[4096*768]; later ctx
constexpr size_t SZ_XB    = (size_t)S_LEN * HDIM * 2;
constexpr size_t OFF_WQKV = OFF_XB + SZ_XB;             // f16[3*768*768]; later PL
constexpr size_t SZ_WQKV  = (size_t)3 * HDIM * HDIM * 2;
constexpr size_t OFF_WO   = OFF_WQKV + SZ_WQKV;         // f16[768*768]
constexpr size_t SZ_WO    = (size_t)HDIM * HDIM * 2;
constexpr size_t OFF_Q    = OFF_WO + SZ_WO;             // f16[12][4096][64]
constexpr size_t SZ_HD    = (size_t)NHEAD * S_LEN * DHEAD * 2;
constexpr size_t OFF_K    = OFF_Q + SZ_HD;              // f16[12][4096][64] compacted (pre-zeroed)
constexpr size_t OFF_VT   = OFF_K + SZ_HD;              // f16[12][64][4096] transposed+permuted V
constexpr size_t OFF_VR   = OFF_VT + SZ_HD;             // f16[12][4096][64] V rows; later PO split0
constexpr size_t OFF_PO1  = OFF_VR + SZ_HD;             // f16[12][4096][64] PO split1

// ---------------- prep: fp32->fp16 convert + zero Kc + mask compaction ----------------
__global__ __launch_bounds__(256) void k_prep(const float* __restrict__ x,
                                              const float* __restrict__ wq,
                                              const float* __restrict__ wk,
                                              const float* __restrict__ wv,
                                              const float* __restrict__ wo,
                                              const int* __restrict__ mi,
                                              f16* __restrict__ dst,
                                              f16* __restrict__ Kc,
                                              int* __restrict__ pos,
                                              int* __restrict__ meta) {
  __shared__ int s_flag;
  __shared__ int s_cnt[256];
  const int b = blockIdx.x, tid = threadIdx.x;
  if (b < 5376) {
    int i = b * 256 + tid;                   // 1376256 float4 units
    const float* src; int off;
    if (i < 786432) { src = x; off = i; }
    else {
      int j = i - 786432;
      int w = j / 147456;
      off = j - w * 147456;
      src = (w == 0) ? wq : (w == 1) ? wk : (w == 2) ? wv : wo;
    }
    float4 v = ((const float4*)src)[off];
    f16x4 h;
    h[0] = (f16)v.x; h[1] = (f16)v.y; h[2] = (f16)v.z; h[3] = (f16)v.w;
    ((f16x4*)dst)[i] = h;
    return;
  }
  if (b < 6144) {
    int u = (b - 5376) * 512 + tid;
    f16x8 z = {};
    ((f16x8*)Kc)[u] = z;
    ((f16x8*)Kc)[u + 256] = z;
    return;
  }
  // ---- mask block ----
  if (tid == 0) s_flag = 1;
  __syncthreads();
  int bad = 0;
  #pragma unroll
  for (int k = 0; k < 4; ++k) {
    int v = mi[k * 256 + tid];
    if (v != 0 && v != 1) bad = 1;
  }
  if (bad) atomicAnd(&s_flag, 0);
  __syncthreads();
  const int isInt = s_flag;
  const unsigned char* mu8 = (const unsigned char*)mi;
  int keep[16]; int cnt = 0;
  const int s0 = tid * 16;
  #pragma unroll
  for (int k = 0; k < 16; ++k) {
    int mval = isInt ? mi[s0 + k] : (int)mu8[s0 + k];
    keep[k] = (mval == 0) ? 1 : 0;           // True => masked out (excluded)
    cnt += keep[k];
  }
  s_cnt[tid] = cnt;
  __syncthreads();
  for (int off = 1; off < 256; off <<= 1) {
    int t = (tid >= off) ? s_cnt[tid - off] : 0;
    __syncthreads();
    s_cnt[tid] += t;
    __syncthreads();
  }
  int base = s_cnt[tid] - cnt;
  #pragma unroll
  for (int k = 0; k < 16; ++k) {
    pos[s0 + k] = keep[k] ? base : -1;
    base += keep[k];
  }
  if (tid == 255) meta[0] = s_cnt[255];
}

// ---------------- fused QKV projection GEMM ----------------
__global__ __launch_bounds__(256) void k_qkv(
    const f16* __restrict__ xb, const f16* __restrict__ wqkv,
    const float* __restrict__ bq, const float* __restrict__ bk, const float* __restrict__ bv,
    const int* __restrict__ pos,
    f16* __restrict__ Qh, f16* __restrict__ Kc, f16* __restrict__ Vrow) {
  __shared__ __attribute__((aligned(16))) f16 lA[128 * 32];
  __shared__ __attribute__((aligned(16))) f16 lB[128 * 32];
  const int tid = threadIdx.x;
  const int wid = tid >> 6, lane = tid & 63;
  const int quad = lane >> 4, l16 = lane & 15;
  const int wm = wid >> 1, wn = wid & 1;
  const int tn = blockIdx.x;
  const int m0 = blockIdx.y * 128;
  const int mat = tn / 6;
  const int nb = (tn % 6) * 128;
  const f16* wbase = wqkv + (size_t)mat * HDIM * HDIM;

  f32x4 acc[4][4] = {};

  for (int k0 = 0; k0 < HDIM; k0 += 32) {
    #pragma unroll
    for (int iss = 0; iss < 2; ++iss) {
      int c = iss * 256 + tid;
      int row = c >> 2, slot = c & 3;
      int gs = slot ^ swz4(row);
      async_copy16((const char*)(xb + (size_t)(m0 + row) * HDIM + k0) + gs * 16,
                   (char*)lA + (iss * 256 + wid * 64) * 16);
      async_copy16((const char*)(wbase + (size_t)(nb + row) * HDIM + k0) + gs * 16,
                   (char*)lB + (iss * 256 + wid * 64) * 16);
    }
    __syncthreads();
    f16x8 af[4], bf[4];
    #pragma unroll
    for (int mi = 0; mi < 4; ++mi) {
      int row = wm * 64 + mi * 16 + l16;
      af[mi] = *(const f16x8*)&lA[row * 32 + (quad ^ swz4(row)) * 8];
    }
    #pragma unroll
    for (int ni = 0; ni < 4; ++ni) {
      int row = wn * 64 + ni * 16 + l16;
      bf[ni] = *(const f16x8*)&lB[row * 32 + (quad ^ swz4(row)) * 8];
    }
    #pragma unroll
    for (int mi = 0; mi < 4; ++mi)
      #pragma unroll
      for (int ni = 0; ni < 4; ++ni)
        acc[mi][ni] = __builtin_amdgcn_mfma_f32_16x16x32_f16(af[mi], bf[ni], acc[mi][ni], 0, 0, 0);
    __syncthreads();
  }

  const float* bias = (mat == 0) ? bq : (mat == 1) ? bk : bv;
  const float qscale = 0.125f * 1.44269504088896341f;  // 1/sqrt(64) * log2(e)
  f16* kvdst = (mat == 1) ? Kc : Vrow;
  #pragma unroll
  for (int mi = 0; mi < 4; ++mi) {
    int srow = m0 + wm * 64 + mi * 16 + quad * 4;
    #pragma unroll
    for (int ni = 0; ni < 4; ++ni) {
      int n = nb + wn * 64 + ni * 16 + l16;
      int head = n >> 6, d = n & 63;
      float b = bias[n];
      #pragma unroll
      for (int r = 0; r < 4; ++r) {
        int s = srow + r;
        float val = acc[mi][ni][r] + b;
        if (mat == 0) {
          Qh[((size_t)head * S_LEN + s) * DHEAD + d] = (f16)(val * qscale);
        } else {
          int p = pos[s];
          if (p >= 0)
            kvdst[((size_t)head * S_LEN + p) * DHEAD + d] = (f16)val;
        }
      }
    }
  }
}

// ---------------- V transpose [h][p][d] -> [h][d][rho], key order bit-swapped ----------------
// rho-position holds key with bits 2<->3 swapped (within each 16-group), so that the PV
// A-fragment in k_attn is the lane's own contiguous C-regs (no cross-lane exchange).
__global__ __launch_bounds__(256) void k_vt(const int* __restrict__ meta,
                                            const f16* __restrict__ Vrow,
                                            f16* __restrict__ Vtc) {
  const int kc = meta[0];
  const int kcp = (kc + 63) & ~63;
  const int p0 = blockIdx.x * 64;
  const int h = blockIdx.y;
  if (p0 >= kcp) return;
  __shared__ __attribute__((aligned(16))) f16 lT[64 * 80];   // [d][p], stride 80
  const int tid = threadIdx.x;
  for (int u = tid; u < 512; u += 256) {
    int d8 = u >> 6, p = u & 63;
    f16x8 v = {};
    if (p0 + p < kc) v = *(const f16x8*)&Vrow[((size_t)h * S_LEN + p0 + p) * DHEAD + d8 * 8];
    #pragma unroll
    for (int j = 0; j < 8; ++j) lT[(d8 * 8 + j) * 80 + p] = v[j];
  }
  __syncthreads();
  for (int w = tid; w < 512; w += 256) {
    int d = w >> 3, p8 = w & 7;
    int base16 = (p8 >> 1) * 16, half = p8 & 1;
    f16x4 lo = *(const f16x4*)&lT[d * 80 + base16 + half * 4];
    f16x4 hi = *(const f16x4*)&lT[d * 80 + base16 + 8 + half * 4];
    f16x8 o;
    o[0] = lo[0]; o[1] = lo[1]; o[2] = lo[2]; o[3] = lo[3];
    o[4] = hi[0]; o[5] = hi[1]; o[6] = hi[2]; o[7] = hi[3];
    *(f16x8*)&Vtc[((size_t)h * DHEAD + d) * S_LEN + p0 + p8 * 8] = o;
  }
}

// ---------------- flash attention: 32q/wave, register-P, shared K/V tile ----------------
// grid (32 q-tiles of 128, 12 heads, 2 global key-splits); 4 waves = 4 q-groups
// sharing ONE 16KB K/V tile per iteration. S^T = K.Q^T; P = exp2(S^T) stays in
// C-regs; PV A-frag = own C-regs (V key-permuted by k_vt). No in-block combine.
__global__ __launch_bounds__(256, 3) void k_attn(
    const f16* __restrict__ Qh, const f16* __restrict__ Kc, const f16* __restrict__ Vtc,
    const int* __restrict__ meta, f16* __restrict__ PO0, f16* __restrict__ PO1,
    float* __restrict__ PL) {
  __shared__ __attribute__((aligned(16))) f16 lK[64 * 64];   // [key][d] swizzled, 8KB
  __shared__ __attribute__((aligned(16))) f16 lV[64 * 64];   // [d][rho] swizzled, 8KB
  const int tid = threadIdx.x;
  const int wid = tid >> 6, lane = tid & 63;
  const int hf = lane >> 5, l31 = lane & 31, r7 = l31 & 7;
  const int head = blockIdx.y;
  const int split = blockIdx.z;
  const int q0 = blockIdx.x * 128 + wid * 32;
  const int kc = meta[0];
  const int nkt = (kc + 63) >> 6;
  const int th = nkt >> 1;
  const int t0 = split ? th : 0;
  const int t1 = split ? nkt : th;

  // Q B-frags: lane n = q = l31, k = dc*16 + hf*8 + j  (held in regs whole kernel)
  const f16* Qp = Qh + ((size_t)head * S_LEN + q0 + l31) * DHEAD;
  f16x8 qf[4];
  #pragma unroll
  for (int dc = 0; dc < 4; ++dc) qf[dc] = *(const f16x8*)(Qp + dc * 16 + hf * 8);

  f32x16 accO[2] = {};     // [dh]: O columns dh*32+l31, rows = C-layout
  float lsum = 0.f;

  const char* kbase = (const char*)(Kc + (size_t)head * S_LEN * DHEAD);
  const char* vbase = (const char*)(Vtc + (size_t)head * DHEAD * S_LEN);

  for (int t = t0; t < t1; ++t) {
    const int j0 = t * 64;
    #pragma unroll
    for (int iss = 0; iss < 2; ++iss) {
      int c = iss * 256 + tid;                 // 0..511 chunk id
      int row = c >> 3, slot = c & 7;
      int gs = slot ^ (row & 7);               // 8x16B-slot XOR swizzle
      async_copy16(kbase + (size_t)(j0 + row) * 128 + gs * 16,
                   (char*)lK + (iss * 256 + wid * 64) * 16);
      async_copy16(vbase + (size_t)row * (S_LEN * 2) + (size_t)j0 * 2 + gs * 16,
                   (char*)lV + (iss * 256 + wid * 64) * 16);
    }
    __syncthreads();

    #pragma unroll
    for (int mh = 0; mh < 2; ++mh) {
      // K A-frags: lane m = key = mh*32 + l31, k = dc*16 + hf*8 + j
      f16x8 af[4];
      const int arow = mh * 32 + l31;
      #pragma unroll
      for (int dc = 0; dc < 4; ++dc)
        af[dc] = *(const f16x8*)&lK[arow * 64 + ((((dc << 1) | hf) ^ r7) * 8)];
      f32x16 s = {};
      #pragma unroll
      for (int dc = 0; dc < 4; ++dc)
        s = __builtin_amdgcn_mfma_f32_32x32x16_f16(af[dc], qf[dc], s, 0, 0, 0);
      #pragma unroll
      for (int u = 0; u < 16; ++u) { s[u] = fast_exp2(s[u]); lsum += s[u]; }
      // PV: A-frag for 16-key chunk c2 = own C-regs [8cc..8cc+7] (V key-permuted)
      #pragma unroll
      for (int cc = 0; cc < 2; ++cc) {
        f16x8 pf;
        #pragma unroll
        for (int u = 0; u < 8; ++u) pf[u] = (f16)s[8 * cc + u];
        const int c2 = mh * 2 + cc;
        #pragma unroll
        for (int dh = 0; dh < 2; ++dh) {
          const int vrow = dh * 32 + l31;
          f16x8 vf = *(const f16x8*)&lV[vrow * 64 + ((((c2 << 1) | hf) ^ r7) * 8)];
          accO[dh] = __builtin_amdgcn_mfma_f32_32x32x16_f16(pf, vf, accO[dh], 0, 0, 0);
        }
      }
    }
    __syncthreads();
  }

  // fold hf halves (each lane summed only 32 of the 64 key-rows per tile)
  lsum += __shfl_xor(lsum, 32);
  // pad keys are zero K rows -> P = 1 exactly; last tile lives in split 1
  if (split == 1) lsum -= (float)(nkt * 64 - kc);
  if (hf == 0)
    PL[((size_t)split * NHEAD + head) * S_LEN + q0 + l31] = lsum;

  f16* PO = split ? PO1 : PO0;
  #pragma unroll
  for (int dh = 0; dh < 2; ++dh)
    #pragma unroll
    for (int reg = 0; reg < 16; ++reg) {
      int row = (reg & 3) + 8 * (reg >> 2) + 4 * hf;
      PO[((size_t)head * S_LEN + q0 + row) * DHEAD + dh * 32 + l31] = (f16)accO[dh][reg];
    }
}

// ---------------- combine key-split partials -> ctx ----------------
__global__ __launch_bounds__(256) void k_comb(const f16* __restrict__ PO0,
                                              const f16* __restrict__ PO1,
                                              const float* __restrict__ PL,
                                              f16* __restrict__ ctx) {
  int u = blockIdx.x * 256 + threadIdx.x;    // 4096 rows * 96 8-wide units
  int s = u / 96;
  int c = u - s * 96;
  int h = c >> 3, db = (c & 7) * 8;
  size_t i0 = ((size_t)h * S_LEN + s) * DHEAD + db;
  f16x8 o0 = *(const f16x8*)(PO0 + i0);
  f16x8 o1 = *(const f16x8*)(PO1 + i0);
  float l = PL[(size_t)h * S_LEN + s] + PL[(size_t)(NHEAD + h) * S_LEN + s];
  float inv = 1.0f / l;
  f16x8 o;
  #pragma unroll
  for (int i = 0; i < 8; ++i) o[i] = (f16)(((float)o0[i] + (float)o1[i]) * inv);
  *(f16x8*)(ctx + (size_t)s * HDIM + h * DHEAD + db) = o;
}

// ---------------- output projection GEMM (fp32 out) ----------------
__global__ __launch_bounds__(256) void k_out(
    const f16* __restrict__ ctx, const f16* __restrict__ wo,
    const float* __restrict__ bo, float* __restrict__ out) {
  __shared__ __attribute__((aligned(16))) f16 lA[128 * 32];
  __shared__ __attribute__((aligned(16))) f16 lB[128 * 32];
  const int tid = threadIdx.x;
  const int wid = tid >> 6, lane = tid & 63;
  const int quad = lane >> 4, l16 = lane & 15;
  const int wm = wid >> 1, wn = wid & 1;
  const int nb = blockIdx.x * 128;
  const int m0 = blockIdx.y * 128;

  f32x4 acc[4][4] = {};

  for (int k0 = 0; k0 < HDIM; k0 += 32) {
    #pragma unroll
    for (int iss = 0; iss < 2; ++iss) {
      int c = iss * 256 + tid;
      int row = c >> 2, slot = c & 3;
      int gs = slot ^ swz4(row);
      async_copy16((const char*)(ctx + (size_t)(m0 + row) * HDIM + k0) + gs * 16,
                   (char*)lA + (iss * 256 + wid * 64) * 16);
      async_copy16((const char*)(wo + (size_t)(nb + row) * HDIM + k0) + gs * 16,
                   (char*)lB + (iss * 256 + wid * 64) * 16);
    }
    __syncthreads();
    f16x8 af[4], bf[4];
    #pragma unroll
    for (int mi = 0; mi < 4; ++mi) {
      int row = wm * 64 + mi * 16 + l16;
      af[mi] = *(const f16x8*)&lA[row * 32 + (quad ^ swz4(row)) * 8];
    }
    #pragma unroll
    for (int ni = 0; ni < 4; ++ni) {
      int row = wn * 64 + ni * 16 + l16;
      bf[ni] = *(const f16x8*)&lB[row * 32 + (quad ^ swz4(row)) * 8];
    }
    #pragma unroll
    for (int mi = 0; mi < 4; ++mi)
      #pragma unroll
      for (int ni = 0; ni < 4; ++ni)
        acc[mi][ni] = __builtin_amdgcn_mfma_f32_16x16x32_f16(af[mi], bf[ni], acc[mi][ni], 0, 0, 0);
    __syncthreads();
  }

  #pragma unroll
  for (int mi = 0; mi < 4; ++mi) {
    int srow = m0 + wm * 64 + mi * 16 + quad * 4;
    #pragma unroll
    for (int ni = 0; ni < 4; ++ni) {
      int n = nb + wn * 64 + ni * 16 + l16;
      float b = bo[n];
      #pragma unroll
      for (int r = 0; r < 4; ++r)
        out[(size_t)(srow + r) * HDIM + n] = acc[mi][ni][r] + b;
    }
  }
}

extern "C" void kernel_launch(void* const* d_in, const int* in_sizes, int n_in,
                              void* d_out, int out_size, void* d_ws, size_t ws_size,
                              hipStream_t stream) {
  const float* x  = (const float*)d_in[0];
  const float* Wq = (const float*)d_in[1];
  const float* bq = (const float*)d_in[2];
  const float* Wk = (const float*)d_in[3];
  const float* bk = (const float*)d_in[4];
  const float* Wv = (const float*)d_in[5];
  const float* bv = (const float*)d_in[6];
  const float* Wo = (const float*)d_in[7];
  const float* bo = (const float*)d_in[8];
  const int*   mask = (const int*)d_in[9];
  float* out = (float*)d_out;

  char* ws = (char*)d_ws;
  int* meta  = (int*)(ws + OFF_META);
  int* pos   = (int*)(ws + OFF_POS);
  f16* xb    = (f16*)(ws + OFF_XB);
  f16* wqkv  = (f16*)(ws + OFF_WQKV);
  f16* wob   = (f16*)(ws + OFF_WO);
  f16* Qh    = (f16*)(ws + OFF_Q);
  f16* Kc    = (f16*)(ws + OFF_K);
  f16* Vtc   = (f16*)(ws + OFF_VT);
  f16* Vrow  = (f16*)(ws + OFF_VR);
  f16* PO0   = (f16*)(ws + OFF_VR);     // reuses Vrow after k_vt
  f16* PO1   = (f16*)(ws + OFF_PO1);
  float* PL  = (float*)(ws + OFF_WQKV); // reuses wqkv after k_qkv
  f16* ctx   = (f16*)(ws + OFF_XB);     // reuses xb after k_qkv

  k_prep<<<dim3(6145), 256, 0, stream>>>(x, Wq, Wk, Wv, Wo, mask, xb, Kc, pos, meta);
  k_qkv<<<dim3(18, 32), 256, 0, stream>>>(xb, wqkv, bq, bk, bv, pos, Qh, Kc, Vrow);
  k_vt<<<dim3(64, NHEAD), 256, 0, stream>>>(meta, Vrow, Vtc);
  k_attn<<<dim3(32, NHEAD, 2), 256, 0, stream>>>(Qh, Kc, Vtc, meta, PO0, PO1, PL);
  k_comb<<<dim3((S_LEN * 96) / 256), 256, 0, stream>>>(PO0, PO1, PL, ctx);
  k_out<<<dim3(6, 32), 256, 0, stream>>>(ctx, wob, bo, out);
}

// Round 7
// 185.972 us; speedup vs baseline: 1.3778x; 1.0039x over previous
//
#include <hip/hip_runtime.h>
#include <stdint.h>

#define S_LEN 4096
#define HDIM  768
#define NHEAD 12
#define DHEAD 64

typedef _Float16 f16;
typedef __attribute__((ext_vector_type(8)))  _Float16 f16x8;
typedef __attribute__((ext_vector_type(4)))  _Float16 f16x4;
typedef __attribute__((ext_vector_type(4)))  float    f32x4;
typedef __attribute__((ext_vector_type(16))) float    f32x16;

typedef __attribute__((address_space(1))) void gv_t;
typedef __attribute__((address_space(3))) void lv_t;

__device__ __forceinline__ void async_copy16(const void* g, void* l) {
  __builtin_amdgcn_global_load_lds((gv_t*)g, (lv_t*)l, 16, 0, 0);
}

__device__ __forceinline__ float fast_exp2(float x) {
#if __has_builtin(__builtin_amdgcn_exp2f)
  return __builtin_amdgcn_exp2f(x);
#else
  return exp2f(x);
#endif
}

__device__ __forceinline__ int swz4(int row) { return (row ^ (row >> 2)) & 3; }

// ---------------- workspace layout (42.5 MB, heavy reuse) ----------------
constexpr size_t OFF_META = 0;                          // int kcount
constexpr size_t OFF_POS  = 256;                        // int[4096]
constexpr size_t OFF_XB   = 65536;                      // f16 x[4096*768]; later ctx
constexpr size_t SZ_XB    = (size_t)S_LEN * HDIM * 2;
constexpr size_t OFF_WQKV = OFF_XB + SZ_XB;             // f16[3*768*768]; later PL
constexpr size_t SZ_WQKV  = (size_t)3 * HDIM * HDIM * 2;
constexpr size_t OFF_WO   = OFF_WQKV + SZ_WQKV;         // f16[768*768]
constexpr size_t SZ_WO    = (size_t)HDIM * HDIM * 2;
constexpr size_t OFF_Q    = OFF_WO + SZ_WO;             // f16[12][4096][64]
constexpr size_t SZ_HD    = (size_t)NHEAD * S_LEN * DHEAD * 2;
constexpr size_t OFF_K    = OFF_Q + SZ_HD;              // f16[12][4096][64] compacted (pre-zeroed)
constexpr size_t OFF_VT   = OFF_K + SZ_HD;              // f16[12][64][4096] transposed+permuted V
constexpr size_t OFF_VR   = OFF_VT + SZ_HD;             // f16[12][4096][64] V rows; later PO split0
constexpr size_t OFF_PO1  = OFF_VR + SZ_HD;             // f16[12][4096][64] PO split1

// ---------------- prep: fp32->fp16 convert + zero Kc + mask compaction ----------------
__global__ __launch_bounds__(256) void k_prep(const float* __restrict__ x,
                                              const float* __restrict__ wq,
                                              const float* __restrict__ wk,
                                              const float* __restrict__ wv,
                                              const float* __restrict__ wo,
                                              const int* __restrict__ mi,
                                              f16* __restrict__ dst,
                                              f16* __restrict__ Kc,
                                              int* __restrict__ pos,
                                              int* __restrict__ meta) {
  __shared__ int s_flag;
  __shared__ int s_cnt[256];
  const int b = blockIdx.x, tid = threadIdx.x;
  if (b < 5376) {
    int i = b * 256 + tid;                   // 1376256 float4 units
    const float* src; int off;
    if (i < 786432) { src = x; off = i; }
    else {
      int j = i - 786432;
      int w = j / 147456;
      off = j - w * 147456;
      src = (w == 0) ? wq : (w == 1) ? wk : (w == 2) ? wv : wo;
    }
    float4 v = ((const float4*)src)[off];
    f16x4 h;
    h[0] = (f16)v.x; h[1] = (f16)v.y; h[2] = (f16)v.z; h[3] = (f16)v.w;
    ((f16x4*)dst)[i] = h;
    return;
  }
  if (b < 6144) {
    int u = (b - 5376) * 512 + tid;
    f16x8 z = {};
    ((f16x8*)Kc)[u] = z;
    ((f16x8*)Kc)[u + 256] = z;
    return;
  }
  // ---- mask block ----
  if (tid == 0) s_flag = 1;
  __syncthreads();
  int bad = 0;
  #pragma unroll
  for (int k = 0; k < 4; ++k) {
    int v = mi[k * 256 + tid];
    if (v != 0 && v != 1) bad = 1;
  }
  if (bad) atomicAnd(&s_flag, 0);
  __syncthreads();
  const int isInt = s_flag;
  const unsigned char* mu8 = (const unsigned char*)mi;
  int keep[16]; int cnt = 0;
  const int s0 = tid * 16;
  #pragma unroll
  for (int k = 0; k < 16; ++k) {
    int mval = isInt ? mi[s0 + k] : (int)mu8[s0 + k];
    keep[k] = (mval == 0) ? 1 : 0;           // True => masked out (excluded)
    cnt += keep[k];
  }
  s_cnt[tid] = cnt;
  __syncthreads();
  for (int off = 1; off < 256; off <<= 1) {
    int t = (tid >= off) ? s_cnt[tid - off] : 0;
    __syncthreads();
    s_cnt[tid] += t;
    __syncthreads();
  }
  int base = s_cnt[tid] - cnt;
  #pragma unroll
  for (int k = 0; k < 16; ++k) {
    pos[s0 + k] = keep[k] ? base : -1;
    base += keep[k];
  }
  if (tid == 255) meta[0] = s_cnt[255];
}

// ---------------- fused QKV projection GEMM (32x32x16 MFMA) ----------------
// C[s,n] = x[s,:].W[n,:] + b[n]; 128x128 tile, wave = 64x64 = 2x2 acc of 32x32.
__global__ __launch_bounds__(256) void k_qkv(
    const f16* __restrict__ xb, const f16* __restrict__ wqkv,
    const float* __restrict__ bq, const float* __restrict__ bk, const float* __restrict__ bv,
    const int* __restrict__ pos,
    f16* __restrict__ Qh, f16* __restrict__ Kc, f16* __restrict__ Vrow) {
  __shared__ __attribute__((aligned(16))) f16 lA[128 * 32];
  __shared__ __attribute__((aligned(16))) f16 lB[128 * 32];
  const int tid = threadIdx.x;
  const int wid = tid >> 6, lane = tid & 63;
  const int hf = lane >> 5, l31 = lane & 31;
  const int wm = wid >> 1, wn = wid & 1;
  const int tn = blockIdx.x;
  const int m0 = blockIdx.y * 128;
  const int mat = tn / 6;
  const int nb = (tn % 6) * 128;
  const f16* wbase = wqkv + (size_t)mat * HDIM * HDIM;

  f32x16 acc[2][2] = {};

  for (int k0 = 0; k0 < HDIM; k0 += 32) {
    #pragma unroll
    for (int iss = 0; iss < 2; ++iss) {
      int c = iss * 256 + tid;
      int row = c >> 2, slot = c & 3;
      int gs = slot ^ swz4(row);
      async_copy16((const char*)(xb + (size_t)(m0 + row) * HDIM + k0) + gs * 16,
                   (char*)lA + (iss * 256 + wid * 64) * 16);
      async_copy16((const char*)(wbase + (size_t)(nb + row) * HDIM + k0) + gs * 16,
                   (char*)lB + (iss * 256 + wid * 64) * 16);
    }
    __syncthreads();
    #pragma unroll
    for (int kk = 0; kk < 2; ++kk) {
      f16x8 af[2], bf[2];
      #pragma unroll
      for (int mi = 0; mi < 2; ++mi) {
        int row = wm * 64 + mi * 32 + l31;
        af[mi] = *(const f16x8*)&lA[row * 32 + (((kk * 2 + hf) ^ swz4(row)) * 8)];
      }
      #pragma unroll
      for (int ni = 0; ni < 2; ++ni) {
        int row = wn * 64 + ni * 32 + l31;
        bf[ni] = *(const f16x8*)&lB[row * 32 + (((kk * 2 + hf) ^ swz4(row)) * 8)];
      }
      #pragma unroll
      for (int mi = 0; mi < 2; ++mi)
        #pragma unroll
        for (int ni = 0; ni < 2; ++ni)
          acc[mi][ni] = __builtin_amdgcn_mfma_f32_32x32x16_f16(af[mi], bf[ni], acc[mi][ni], 0, 0, 0);
    }
    __syncthreads();
  }

  const float* bias = (mat == 0) ? bq : (mat == 1) ? bk : bv;
  const float qscale = 0.125f * 1.44269504088896341f;  // 1/sqrt(64) * log2(e)
  f16* kvdst = (mat == 1) ? Kc : Vrow;
  #pragma unroll
  for (int mi = 0; mi < 2; ++mi) {
    #pragma unroll
    for (int ni = 0; ni < 2; ++ni) {
      int n = nb + wn * 64 + ni * 32 + l31;
      int head = n >> 6, d = n & 63;
      float b = bias[n];
      #pragma unroll
      for (int reg = 0; reg < 16; ++reg) {
        int s = m0 + wm * 64 + mi * 32 + (reg & 3) + 8 * (reg >> 2) + 4 * hf;
        float val = acc[mi][ni][reg] + b;
        if (mat == 0) {
          Qh[((size_t)head * S_LEN + s) * DHEAD + d] = (f16)(val * qscale);
        } else {
          int p = pos[s];
          if (p >= 0)
            kvdst[((size_t)head * S_LEN + p) * DHEAD + d] = (f16)val;
        }
      }
    }
  }
}

// ---------------- V transpose [h][p][d] -> [h][d][rho], key order bit-swapped ----------------
// rho-position holds key with bits 2<->3 swapped (within each 16-group), so that the PV
// A-fragment in k_attn is the lane's own contiguous C-regs (no cross-lane exchange).
__global__ __launch_bounds__(256) void k_vt(const int* __restrict__ meta,
                                            const f16* __restrict__ Vrow,
                                            f16* __restrict__ Vtc) {
  const int kc = meta[0];
  const int kcp = (kc + 63) & ~63;
  const int p0 = blockIdx.x * 64;
  const int h = blockIdx.y;
  if (p0 >= kcp) return;
  __shared__ __attribute__((aligned(16))) f16 lT[64 * 80];   // [d][p], stride 80
  const int tid = threadIdx.x;
  for (int u = tid; u < 512; u += 256) {
    int d8 = u >> 6, p = u & 63;
    f16x8 v = {};
    if (p0 + p < kc) v = *(const f16x8*)&Vrow[((size_t)h * S_LEN + p0 + p) * DHEAD + d8 * 8];
    #pragma unroll
    for (int j = 0; j < 8; ++j) lT[(d8 * 8 + j) * 80 + p] = v[j];
  }
  __syncthreads();
  for (int w = tid; w < 512; w += 256) {
    int d = w >> 3, p8 = w & 7;
    int base16 = (p8 >> 1) * 16, half = p8 & 1;
    f16x4 lo = *(const f16x4*)&lT[d * 80 + base16 + half * 4];
    f16x4 hi = *(const f16x4*)&lT[d * 80 + base16 + 8 + half * 4];
    f16x8 o;
    o[0] = lo[0]; o[1] = lo[1]; o[2] = lo[2]; o[3] = lo[3];
    o[4] = hi[0]; o[5] = hi[1]; o[6] = hi[2]; o[7] = hi[3];
    *(f16x8*)&Vtc[((size_t)h * DHEAD + d) * S_LEN + p0 + p8 * 8] = o;
  }
}

// ---------------- flash attention: 32q/wave, register-P, shared K/V tile ----------------
__global__ __launch_bounds__(256, 3) void k_attn(
    const f16* __restrict__ Qh, const f16* __restrict__ Kc, const f16* __restrict__ Vtc,
    const int* __restrict__ meta, f16* __restrict__ PO0, f16* __restrict__ PO1,
    float* __restrict__ PL) {
  __shared__ __attribute__((aligned(16))) f16 lK[64 * 64];   // [key][d] swizzled, 8KB
  __shared__ __attribute__((aligned(16))) f16 lV[64 * 64];   // [d][rho] swizzled, 8KB
  const int tid = threadIdx.x;
  const int wid = tid >> 6, lane = tid & 63;
  const int hf = lane >> 5, l31 = lane & 31, r7 = l31 & 7;
  const int head = blockIdx.y;
  const int split = blockIdx.z;
  const int q0 = blockIdx.x * 128 + wid * 32;
  const int kc = meta[0];
  const int nkt = (kc + 63) >> 6;
  const int th = nkt >> 1;
  const int t0 = split ? th : 0;
  const int t1 = split ? nkt : th;

  // Q B-frags: lane n = q = l31, k = dc*16 + hf*8 + j  (held in regs whole kernel)
  const f16* Qp = Qh + ((size_t)head * S_LEN + q0 + l31) * DHEAD;
  f16x8 qf[4];
  #pragma unroll
  for (int dc = 0; dc < 4; ++dc) qf[dc] = *(const f16x8*)(Qp + dc * 16 + hf * 8);

  f32x16 accO[2] = {};     // [dh]: O columns dh*32+l31, rows = C-layout
  float lsum = 0.f;

  const char* kbase = (const char*)(Kc + (size_t)head * S_LEN * DHEAD);
  const char* vbase = (const char*)(Vtc + (size_t)head * DHEAD * S_LEN);

  for (int t = t0; t < t1; ++t) {
    const int j0 = t * 64;
    #pragma unroll
    for (int iss = 0; iss < 2; ++iss) {
      int c = iss * 256 + tid;                 // 0..511 chunk id
      int row = c >> 3, slot = c & 7;
      int gs = slot ^ (row & 7);               // 8x16B-slot XOR swizzle
      async_copy16(kbase + (size_t)(j0 + row) * 128 + gs * 16,
                   (char*)lK + (iss * 256 + wid * 64) * 16);
      async_copy16(vbase + (size_t)row * (S_LEN * 2) + (size_t)j0 * 2 + gs * 16,
                   (char*)lV + (iss * 256 + wid * 64) * 16);
    }
    __syncthreads();

    #pragma unroll
    for (int mh = 0; mh < 2; ++mh) {
      // K A-frags: lane m = key = mh*32 + l31, k = dc*16 + hf*8 + j
      f16x8 af[4];
      const int arow = mh * 32 + l31;
      #pragma unroll
      for (int dc = 0; dc < 4; ++dc)
        af[dc] = *(const f16x8*)&lK[arow * 64 + ((((dc << 1) | hf) ^ r7) * 8)];
      f32x16 s = {};
      #pragma unroll
      for (int dc = 0; dc < 4; ++dc)
        s = __builtin_amdgcn_mfma_f32_32x32x16_f16(af[dc], qf[dc], s, 0, 0, 0);
      #pragma unroll
      for (int u = 0; u < 16; ++u) { s[u] = fast_exp2(s[u]); lsum += s[u]; }
      // PV: A-frag for 16-key chunk c2 = own C-regs [8cc..8cc+7] (V key-permuted)
      #pragma unroll
      for (int cc = 0; cc < 2; ++cc) {
        f16x8 pf;
        #pragma unroll
        for (int u = 0; u < 8; ++u) pf[u] = (f16)s[8 * cc + u];
        const int c2 = mh * 2 + cc;
        #pragma unroll
        for (int dh = 0; dh < 2; ++dh) {
          const int vrow = dh * 32 + l31;
          f16x8 vf = *(const f16x8*)&lV[vrow * 64 + ((((c2 << 1) | hf) ^ r7) * 8)];
          accO[dh] = __builtin_amdgcn_mfma_f32_32x32x16_f16(pf, vf, accO[dh], 0, 0, 0);
        }
      }
    }
    __syncthreads();
  }

  // fold hf halves (each lane summed only 32 of the 64 key-rows per tile)
  lsum += __shfl_xor(lsum, 32);
  // pad keys are zero K rows -> P = 1 exactly; last tile lives in split 1
  if (split == 1) lsum -= (float)(nkt * 64 - kc);
  if (hf == 0)
    PL[((size_t)split * NHEAD + head) * S_LEN + q0 + l31] = lsum;

  f16* PO = split ? PO1 : PO0;
  #pragma unroll
  for (int dh = 0; dh < 2; ++dh)
    #pragma unroll
    for (int reg = 0; reg < 16; ++reg) {
      int row = (reg & 3) + 8 * (reg >> 2) + 4 * hf;
      PO[((size_t)head * S_LEN + q0 + row) * DHEAD + dh * 32 + l31] = (f16)accO[dh][reg];
    }
}

// ---------------- combine key-split partials -> ctx ----------------
__global__ __launch_bounds__(256) void k_comb(const f16* __restrict__ PO0,
                                              const f16* __restrict__ PO1,
                                              const float* __restrict__ PL,
                                              f16* __restrict__ ctx) {
  int u = blockIdx.x * 256 + threadIdx.x;    // 4096 rows * 96 8-wide units
  int s = u / 96;
  int c = u - s * 96;
  int h = c >> 3, db = (c & 7) * 8;
  size_t i0 = ((size_t)h * S_LEN + s) * DHEAD + db;
  f16x8 o0 = *(const f16x8*)(PO0 + i0);
  f16x8 o1 = *(const f16x8*)(PO1 + i0);
  float l = PL[(size_t)h * S_LEN + s] + PL[(size_t)(NHEAD + h) * S_LEN + s];
  float inv = 1.0f / l;
  f16x8 o;
  #pragma unroll
  for (int i = 0; i < 8; ++i) o[i] = (f16)(((float)o0[i] + (float)o1[i]) * inv);
  *(f16x8*)(ctx + (size_t)s * HDIM + h * DHEAD + db) = o;
}

// ---------------- output projection GEMM (32x32x16 MFMA, fp32 out) ----------------
__global__ __launch_bounds__(256) void k_out(
    const f16* __restrict__ ctx, const f16* __restrict__ wo,
    const float* __restrict__ bo, float* __restrict__ out) {
  __shared__ __attribute__((aligned(16))) f16 lA[128 * 32];
  __shared__ __attribute__((aligned(16))) f16 lB[128 * 32];
  const int tid = threadIdx.x;
  const int wid = tid >> 6, lane = tid & 63;
  const int hf = lane >> 5, l31 = lane & 31;
  const int wm = wid >> 1, wn = wid & 1;
  const int nb = blockIdx.x * 128;
  const int m0 = blockIdx.y * 128;

  f32x16 acc[2][2] = {};

  for (int k0 = 0; k0 < HDIM; k0 += 32) {
    #pragma unroll
    for (int iss = 0; iss < 2; ++iss) {
      int c = iss * 256 + tid;
      int row = c >> 2, slot = c & 3;
      int gs = slot ^ swz4(row);
      async_copy16((const char*)(ctx + (size_t)(m0 + row) * HDIM + k0) + gs * 16,
                   (char*)lA + (iss * 256 + wid * 64) * 16);
      async_copy16((const char*)(wo + (size_t)(nb + row) * HDIM + k0) + gs * 16,
                   (char*)lB + (iss * 256 + wid * 64) * 16);
    }
    __syncthreads();
    #pragma unroll
    for (int kk = 0; kk < 2; ++kk) {
      f16x8 af[2], bf[2];
      #pragma unroll
      for (int mi = 0; mi < 2; ++mi) {
        int row = wm * 64 + mi * 32 + l31;
        af[mi] = *(const f16x8*)&lA[row * 32 + (((kk * 2 + hf) ^ swz4(row)) * 8)];
      }
      #pragma unroll
      for (int ni = 0; ni < 2; ++ni) {
        int row = wn * 64 + ni * 32 + l31;
        bf[ni] = *(const f16x8*)&lB[row * 32 + (((kk * 2 + hf) ^ swz4(row)) * 8)];
      }
      #pragma unroll
      for (int mi = 0; mi < 2; ++mi)
        #pragma unroll
        for (int ni = 0; ni < 2; ++ni)
          acc[mi][ni] = __builtin_amdgcn_mfma_f32_32x32x16_f16(af[mi], bf[ni], acc[mi][ni], 0, 0, 0);
    }
    __syncthreads();
  }

  #pragma unroll
  for (int mi = 0; mi < 2; ++mi) {
    #pragma unroll
    for (int ni = 0; ni < 2; ++ni) {
      int n = nb + wn * 64 + ni * 32 + l31;
      float b = bo[n];
      #pragma unroll
      for (int reg = 0; reg < 16; ++reg) {
        int s = m0 + wm * 64 + mi * 32 + (reg & 3) + 8 * (reg >> 2) + 4 * hf;
        out[(size_t)s * HDIM + n] = acc[mi][ni][reg] + b;
      }
    }
  }
}

extern "C" void kernel_launch(void* const* d_in, const int* in_sizes, int n_in,
                              void* d_out, int out_size, void* d_ws, size_t ws_size,
                              hipStream_t stream) {
  const float* x  = (const float*)d_in[0];
  const float* Wq = (const float*)d_in[1];
  const float* bq = (const float*)d_in[2];
  const float* Wk = (const float*)d_in[3];
  const float* bk = (const float*)d_in[4];
  const float* Wv = (const float*)d_in[5];
  const float* bv = (const float*)d_in[6];
  const float* Wo = (const float*)d_in[7];
  const float* bo = (const float*)d_in[8];
  const int*   mask = (const int*)d_in[9];
  float* out = (float*)d_out;

  char* ws = (char*)d_ws;
  int* meta  = (int*)(ws + OFF_META);
  int* pos   = (int*)(ws + OFF_POS);
  f16* xb    = (f16*)(ws + OFF_XB);
  f16* wqkv  = (f16*)(ws + OFF_WQKV);
  f16* wob   = (f16*)(ws + OFF_WO);
  f16* Qh    = (f16*)(ws + OFF_Q);
  f16* Kc    = (f16*)(ws + OFF_K);
  f16* Vtc   = (f16*)(ws + OFF_VT);
  f16* Vrow  = (f16*)(ws + OFF_VR);
  f16* PO0   = (f16*)(ws + OFF_VR);     // reuses Vrow after k_vt
  f16* PO1   = (f16*)(ws + OFF_PO1);
  float* PL  = (float*)(ws + OFF_WQKV); // reuses wqkv after k_qkv
  f16* ctx   = (f16*)(ws + OFF_XB);     // reuses xb after k_qkv

  k_prep<<<dim3(6145), 256, 0, stream>>>(x, Wq, Wk, Wv, Wo, mask, xb, Kc, pos, meta);
  k_qkv<<<dim3(18, 32), 256, 0, stream>>>(xb, wqkv, bq, bk, bv, pos, Qh, Kc, Vrow);
  k_vt<<<dim3(64, NHEAD), 256, 0, stream>>>(meta, Vrow, Vtc);
  k_attn<<<dim3(32, NHEAD, 2), 256, 0, stream>>>(Qh, Kc, Vtc, meta, PO0, PO1, PL);
  k_comb<<<dim3((S_LEN * 96) / 256), 256, 0, stream>>>(PO0, PO1, PL, ctx);
  k_out<<<dim3(6, 32), 256, 0, stream>>>(ctx, wob, bo, out);
}